// Round 1
// baseline (1201.790 us; speedup 1.0000x reference)
//
#include <hip/hip_runtime.h>
#include <math.h>

// ---------------- workspace layout ----------------
// floats
#define WS_M1_F    0           // 4096 f32
#define WS_M2_F    4096        // 4096 f32
#define WS_BNSC_F  8192        // 64 f32
#define WS_BNSH_F  8256        // 64 f32
#define WS_WT_F    8448        // 12288 f32 (conv_w transposed [ik][o])
// bytes
#define WS_W1PK_B  83968       // 32768 u32 (attn_w1 packed fp16 pairs [q][k]) = 131072 B
#define WS_POTS_B  215040      // pots fp16 [chunk][15][2048]
#define PER_BATCH_POTS_B 61440 // 15*2048*2
#define PER_BATCH_CTX_B  8192  // 2048*4

// ---------------- fp16 helpers ----------------
typedef _Float16 half2v __attribute__((ext_vector_type(2)));

__device__ __forceinline__ unsigned short f2h_u(float x) {
  _Float16 h = (_Float16)x;
  union { _Float16 h; unsigned short u; } v; v.h = h; return v.u;
}
__device__ __forceinline__ float h2f_lo(unsigned int u) {
  union { unsigned short s; _Float16 h; } v; v.s = (unsigned short)(u & 0xffffu); return (float)v.h;
}
__device__ __forceinline__ float h2f_hi(unsigned int u) {
  union { unsigned short s; _Float16 h; } v; v.s = (unsigned short)(u >> 16); return (float)v.h;
}
__device__ __forceinline__ float dot2h(unsigned int a, unsigned int b, float c) {
#if __has_builtin(__builtin_amdgcn_fdot2)
  union { unsigned int u; half2v h; } va, vb; va.u = a; vb.u = b;
  return __builtin_amdgcn_fdot2(va.h, vb.h, c, false);
#else
  return fmaf(h2f_hi(a), h2f_hi(b), fmaf(h2f_lo(a), h2f_lo(b), c));
#endif
}

// ================= K1: prep =================
__global__ __launch_bounds__(256) void k_prep(
    const float* __restrict__ mask1, const float* __restrict__ mask2,
    const float* __restrict__ conv_w, const float* __restrict__ conv_b,
    const float* __restrict__ bn_gamma, const float* __restrict__ bn_beta,
    const float* __restrict__ bn_mean, const float* __restrict__ bn_var,
    const float* __restrict__ attn_w1,
    float* __restrict__ wsf, unsigned int* __restrict__ w1pk)
{
  const int tid = threadIdx.x;
  float* m1 = wsf + WS_M1_F;
  float* m2 = wsf + WS_M2_F;
  float* bnsc = wsf + WS_BNSC_F;
  float* bnsh = wsf + WS_BNSH_F;
  float* wT = wsf + WS_WT_F;
  for (int e = tid; e < 4096; e += 256) {
    int i = e >> 6, j = e & 63;
    float s1 = mask1[e] + mask1[j * 64 + i];
    float s2 = mask2[e] + mask2[j * 64 + i];
    m1[e] = 0.5f / (1.f + expf(-s1));
    m2[e] = 0.5f / (1.f + expf(-s2));
  }
  if (tid < 64) {
    float sc = bn_gamma[tid] * rsqrtf(bn_var[tid] + 1e-5f);
    bnsc[tid] = sc;
    bnsh[tid] = (conv_b[tid] - bn_mean[tid]) * sc + bn_beta[tid];
  }
  for (int e = tid; e < 12288; e += 256) {
    int o = e / 192, ik = e % 192;
    wT[ik * 64 + o] = conv_w[e];
  }
  for (int e = tid; e < 32768; e += 256) {
    int q = e >> 5, k = e & 31;
    unsigned int lo = f2h_u(attn_w1[(2 * q) * 32 + k]);
    unsigned int hi = f2h_u(attn_w1[(2 * q + 1) * 32 + k]);
    w1pk[e] = lo | (hi << 16);
  }
}

// ================= K2: recurrence (one block per batch) =================
__global__ __launch_bounds__(256) void k_main(
    const float* __restrict__ L_norm, const float* __restrict__ X_seq,
    const float* __restrict__ gcn1_w, const float* __restrict__ gcn1_b,
    const float* __restrict__ gcn2_w, const float* __restrict__ gcn2_b,
    const float* __restrict__ beta2p,
    const float* __restrict__ wsf, unsigned short* __restrict__ pots,
    int b0)
{
  __shared__ float L1t[64 * 65];     // L_norm*m1, row stride 65 (conflict-free b32)
  __shared__ float xraw[960];        // X_seq[b] [t][n]
  __shared__ float xcur[960];        // conv+bn output [t][o]
  __shared__ float spkt[64];
  __shared__ float z1s[64];
  __shared__ float spk1b[64 * 17];   // spk1 [j][c], stride 17
  __shared__ float HT[32 * 68];      // H^T [h][j], stride 68 (16B-aligned quads)
  __shared__ float w2l[512];         // gcn2_w [16][32]

  const int tid = threadIdx.x;
  const int lane = tid & 63;
  const int wv = tid >> 6;
  const int b = b0 + blockIdx.x;

  const float* m1 = wsf + WS_M1_F;
  const float* m2 = wsf + WS_M2_F;
  const float* bnsc = wsf + WS_BNSC_F;
  const float* bnsh = wsf + WS_BNSH_F;
  const float* wT = wsf + WS_WT_F;

  // stage X_seq[b]
  for (int e = tid; e < 960; e += 256) xraw[e] = X_seq[(size_t)b * 960 + e];
  // stage gcn2_w
  w2l[tid] = gcn2_w[tid];
  w2l[tid + 256] = gcn2_w[tid + 256];
  // stage L1 = L_norm*m1 into LDS
  {
    const float* Lb = L_norm + (size_t)b * 4096;
    for (int e = tid; e < 4096; e += 256) {
      int n = e >> 6, j = e & 63;
      L1t[n * 65 + j] = Lb[e] * m1[e];
    }
  }
  // L2 row (row = lane) in registers, shared per-wave copies
  float L2row[64];
  {
    const float* Lb = L_norm + (size_t)b * 4096 + lane * 64;
    const float* m2r = m2 + lane * 64;
#pragma unroll
    for (int j4 = 0; j4 < 16; ++j4) {
      float4 lv = *(const float4*)(Lb + 4 * j4);
      float4 mv = *(const float4*)(m2r + 4 * j4);
      L2row[4 * j4 + 0] = lv.x * mv.x;
      L2row[4 * j4 + 1] = lv.y * mv.y;
      L2row[4 * j4 + 2] = lv.z * mv.z;
      L2row[4 * j4 + 3] = lv.w * mv.w;
    }
  }
  __syncthreads();

  // causal conv1d + BN -> xcur[t][o]; wave wv handles t = wv, wv+4, wv+8, wv+12
  {
    const int o = lane;
    const int t0 = wv, t1 = wv + 4, t2 = wv + 8, t3 = wv + 12;
    float a0 = 0.f, a1 = 0.f, a2 = 0.f, a3 = 0.f;
    for (int i = 0; i < 64; ++i) {
      const float w0 = wT[(3 * i + 0) * 64 + o];
      const float w1 = wT[(3 * i + 1) * 64 + o];
      const float w2 = wT[(3 * i + 2) * 64 + o];
      float xa = (t0 >= 2) ? xraw[(t0 - 2) * 64 + i] : 0.f;
      float xb = (t0 >= 1) ? xraw[(t0 - 1) * 64 + i] : 0.f;
      a0 += w0 * xa + w1 * xb + w2 * xraw[t0 * 64 + i];
      a1 += w0 * xraw[(t1 - 2) * 64 + i] + w1 * xraw[(t1 - 1) * 64 + i] + w2 * xraw[t1 * 64 + i];
      a2 += w0 * xraw[(t2 - 2) * 64 + i] + w1 * xraw[(t2 - 1) * 64 + i] + w2 * xraw[t2 * 64 + i];
      if (t3 < 15)
        a3 += w0 * xraw[(t3 - 2) * 64 + i] + w1 * xraw[(t3 - 1) * 64 + i] + w2 * xraw[t3 * 64 + i];
    }
    const float sc = bnsc[o], sh = bnsh[o];
    xcur[t0 * 64 + o] = a0 * sc + sh;
    xcur[t1 * 64 + o] = a1 * sc + sh;
    xcur[t2 * 64 + o] = a2 * sc + sh;
    if (t3 < 15) xcur[t3 * 64 + o] = a3 * sc + sh;
  }

  // per-thread constants
  float w1r[4], b1r[4];
  {
    int c0 = (tid & 3) * 4;
#pragma unroll
    for (int d = 0; d < 4; ++d) { w1r[d] = gcn1_w[c0 + d]; b1r[d] = gcn1_b[c0 + d]; }
  }
  float b2r[8];
  {
    int h0 = wv * 8;
#pragma unroll
    for (int d = 0; d < 8; ++d) b2r[d] = gcn2_b[h0 + d];
  }
  const float beta2 = beta2p[0];

  float mem_t = 0.f;
  float memg1[4] = {0.f, 0.f, 0.f, 0.f};
  float memg2[8] = {0.f, 0.f, 0.f, 0.f, 0.f, 0.f, 0.f, 0.f};
  unsigned short* potsb = pots + (size_t)blockIdx.x * 30720 + lane * 32 + wv * 8;

  __syncthreads();

  for (int t = 0; t < 15; ++t) {
    // ---- input LIF + z1 = L1 @ spk_t (wave 0 only) ----
    if (tid < 64) {
      float reset = (mem_t > 1.f) ? 1.f : 0.f;
      mem_t = 0.9f * mem_t + xcur[t * 64 + tid] - reset;
      spkt[tid] = (mem_t > 1.f) ? 1.f : 0.f;
      float z = 0.f;
      const float* r = L1t + tid * 65;
#pragma unroll
      for (int j = 0; j < 64; ++j) z += r[j] * spkt[j];
      z1s[tid] = z;
    }
    __syncthreads();
    // ---- layer-1 LIF: cur1 = z1 * gcn1_w + b1 ----
    {
      const float zz = z1s[tid >> 2];
      const int base = (tid >> 2) * 17 + (tid & 3) * 4;
#pragma unroll
      for (int d = 0; d < 4; ++d) {
        float cur = zz * w1r[d] + b1r[d];
        float rs = (memg1[d] > 1.f) ? 1.f : 0.f;
        memg1[d] = 0.85f * memg1[d] + cur - rs;
        spk1b[base + d] = (memg1[d] > 1.f) ? 1.f : 0.f;
      }
    }
    __syncthreads();
    // ---- H = spk1 @ W2  (thread: j = lane, h = wv*8..+7) ----
    {
      const int h0 = wv * 8;
      float hv[8] = {0.f, 0.f, 0.f, 0.f, 0.f, 0.f, 0.f, 0.f};
#pragma unroll
      for (int c = 0; c < 16; ++c) {
        const float s = spk1b[lane * 17 + c];
        const float4 wa = *(const float4*)&w2l[c * 32 + h0];
        const float4 wb = *(const float4*)&w2l[c * 32 + h0 + 4];
        hv[0] = fmaf(s, wa.x, hv[0]); hv[1] = fmaf(s, wa.y, hv[1]);
        hv[2] = fmaf(s, wa.z, hv[2]); hv[3] = fmaf(s, wa.w, hv[3]);
        hv[4] = fmaf(s, wb.x, hv[4]); hv[5] = fmaf(s, wb.y, hv[5]);
        hv[6] = fmaf(s, wb.z, hv[6]); hv[7] = fmaf(s, wb.w, hv[7]);
      }
#pragma unroll
      for (int d = 0; d < 8; ++d) HT[(h0 + d) * 68 + lane] = hv[d];
      // no barrier needed: same wave writes and reads its own HT rows
    }
    // ---- cur2 = L2 @ H ; layer-2 LIF ; store pots (fp16) ----
    {
      const int h0 = wv * 8;
      float acc[8] = {0.f, 0.f, 0.f, 0.f, 0.f, 0.f, 0.f, 0.f};
#pragma unroll
      for (int j4 = 0; j4 < 16; ++j4) {
        const float l0 = L2row[4 * j4 + 0];
        const float l1 = L2row[4 * j4 + 1];
        const float l2 = L2row[4 * j4 + 2];
        const float l3 = L2row[4 * j4 + 3];
#pragma unroll
        for (int d = 0; d < 8; ++d) {
          const float4 hq = *(const float4*)&HT[(h0 + d) * 68 + 4 * j4];
          acc[d] += l0 * hq.x + l1 * hq.y + l2 * hq.z + l3 * hq.w;
        }
      }
#pragma unroll
      for (int d = 0; d < 8; ++d) {
        float cur = acc[d] + b2r[d];
        float rs = (memg2[d] > 1.f) ? 1.f : 0.f;
        memg2[d] = beta2 * memg2[d] + cur - rs;
      }
      uint4 pk;
      pk.x = (unsigned int)f2h_u(memg2[0]) | ((unsigned int)f2h_u(memg2[1]) << 16);
      pk.y = (unsigned int)f2h_u(memg2[2]) | ((unsigned int)f2h_u(memg2[3]) << 16);
      pk.z = (unsigned int)f2h_u(memg2[4]) | ((unsigned int)f2h_u(memg2[5]) << 16);
      pk.w = (unsigned int)f2h_u(memg2[6]) | ((unsigned int)f2h_u(memg2[7]) << 16);
      *((uint4*)(potsb + (size_t)t * 2048)) = pk;
    }
    __syncthreads();
  }
}

// ================= K3: attention (one block per batch) =================
__global__ __launch_bounds__(256) void k_attn(
    const unsigned short* __restrict__ pots,
    const unsigned int* __restrict__ w1pk,
    const float* __restrict__ attn_b1, const float* __restrict__ attn_w2,
    const float* __restrict__ attn_b2,
    float* __restrict__ ctx)
{
  __shared__ unsigned int potsu[15 * 512]; // fp16-pair view of half the i range
  __shared__ float red[15 * 256];
  __shared__ float scores[16];
  const int tid = threadIdx.x;
  const int k = tid & 31;
  const int g = tid >> 5; // 0..7 : i-slice group
  const unsigned int* pg = (const unsigned int*)pots + (size_t)blockIdx.x * 15360;

  float p[15];
#pragma unroll
  for (int t = 0; t < 15; ++t) p[t] = 0.f;

  for (int s = 0; s < 2; ++s) {
    for (int e = tid; e < 7680; e += 256) {
      int t = e >> 9, q = e & 511;
      potsu[e] = pg[t * 1024 + s * 512 + q];
    }
    __syncthreads();
    const unsigned int* wp = w1pk + (size_t)(s * 512 + g * 64) * 32 + k;
#pragma unroll 4
    for (int j = 0; j < 64; ++j) {
      const unsigned int wvp = wp[j * 32];
#pragma unroll
      for (int t = 0; t < 15; ++t) {
        p[t] = dot2h(potsu[t * 512 + g * 64 + j], wvp, p[t]);
      }
    }
    __syncthreads();
  }
#pragma unroll
  for (int t = 0; t < 15; ++t) red[t * 256 + tid] = p[t];
  __syncthreads();
  {
    const float b1k = attn_b1[k];
    const float w2k = attn_w2[k];
    float vA = b1k;
#pragma unroll
    for (int gg = 0; gg < 8; ++gg) vA += red[g * 256 + gg * 32 + k];
    float sA = tanhf(vA) * w2k;
    float sB = 0.f;
    const int tb = g + 8;
    if (tb < 15) {
      float vB = b1k;
#pragma unroll
      for (int gg = 0; gg < 8; ++gg) vB += red[tb * 256 + gg * 32 + k];
      sB = tanhf(vB) * w2k;
    }
#pragma unroll
    for (int m = 16; m >= 1; m >>= 1) {
      sA += __shfl_xor(sA, m, 64);
      sB += __shfl_xor(sB, m, 64);
    }
    if (k == 0) {
      scores[g] = sA + attn_b2[0];
      if (tb < 15) scores[tb] = sB + attn_b2[0];
    }
  }
  __syncthreads();
  // softmax weights (every thread)
  float wt[15];
  float mx = scores[0];
#pragma unroll
  for (int t = 1; t < 15; ++t) mx = fmaxf(mx, scores[t]);
  float den = 0.f;
#pragma unroll
  for (int t = 0; t < 15; ++t) { wt[t] = expf(scores[t] - mx); den += wt[t]; }
  const float inv = 1.f / den;
  // ctx = sum_t w_t * pots_t  (thread owns 8 contiguous i)
  float c8[8] = {0.f, 0.f, 0.f, 0.f, 0.f, 0.f, 0.f, 0.f};
  const unsigned short* pp = pots + (size_t)blockIdx.x * 30720 + tid * 8;
  for (int t = 0; t < 15; ++t) {
    uint4 u = *(const uint4*)(pp + (size_t)t * 2048);
    const float w = wt[t] * inv;
    c8[0] += w * h2f_lo(u.x); c8[1] += w * h2f_hi(u.x);
    c8[2] += w * h2f_lo(u.y); c8[3] += w * h2f_hi(u.y);
    c8[4] += w * h2f_lo(u.z); c8[5] += w * h2f_hi(u.z);
    c8[6] += w * h2f_lo(u.w); c8[7] += w * h2f_hi(u.w);
  }
  float* cb = ctx + (size_t)blockIdx.x * 2048 + tid * 8;
  *(float4*)cb = make_float4(c8[0], c8[1], c8[2], c8[3]);
  *(float4*)(cb + 4) = make_float4(c8[4], c8[5], c8[6], c8[7]);
}

// ================= K4: classifier (16 rows per block) =================
__global__ __launch_bounds__(256) void k_cls(
    const float* __restrict__ ctx,
    const float* __restrict__ cls_w1, const float* __restrict__ cls_b1,
    const float* __restrict__ ln_g, const float* __restrict__ ln_b,
    const float* __restrict__ cls_w2, const float* __restrict__ cls_b2,
    float* __restrict__ out, int b0)
{
  __shared__ float Ach[16 * 65];
  __shared__ float Bch[64 * 132];
  __shared__ float hbuf[16 * 132];
  const int tid = threadIdx.x;
  const int rp = tid & 7;   // row pair id
  const int cq = tid >> 3;  // 0..31 col quad
  const int r0l = blockIdx.x * 16;

  float acc0[4] = {0.f, 0.f, 0.f, 0.f};
  float acc1[4] = {0.f, 0.f, 0.f, 0.f};
  for (int kc = 0; kc < 2048; kc += 64) {
    {
      int f = tid * 4;
      int r = f >> 6, kk = f & 63;
      float4 v = *(const float4*)(ctx + (size_t)(r0l + r) * 2048 + kc + kk);
      Ach[r * 65 + kk + 0] = v.x;
      Ach[r * 65 + kk + 1] = v.y;
      Ach[r * 65 + kk + 2] = v.z;
      Ach[r * 65 + kk + 3] = v.w;
    }
#pragma unroll
    for (int q = 0; q < 8; ++q) {
      int f = tid * 4 + q * 1024;
      int kk = f >> 7, c = f & 127;
      float4 v = *(const float4*)(cls_w1 + (size_t)(kc + kk) * 128 + c);
      *(float4*)&Bch[kk * 132 + c] = v;
    }
    __syncthreads();
#pragma unroll 8
    for (int kk = 0; kk < 64; ++kk) {
      const float a0 = Ach[(2 * rp) * 65 + kk];
      const float a1 = Ach[(2 * rp + 1) * 65 + kk];
      const float4 bv = *(const float4*)&Bch[kk * 132 + cq * 4];
      acc0[0] = fmaf(a0, bv.x, acc0[0]); acc0[1] = fmaf(a0, bv.y, acc0[1]);
      acc0[2] = fmaf(a0, bv.z, acc0[2]); acc0[3] = fmaf(a0, bv.w, acc0[3]);
      acc1[0] = fmaf(a1, bv.x, acc1[0]); acc1[1] = fmaf(a1, bv.y, acc1[1]);
      acc1[2] = fmaf(a1, bv.z, acc1[2]); acc1[3] = fmaf(a1, bv.w, acc1[3]);
    }
    __syncthreads();
  }
  {
    const float4 bb = *(const float4*)(cls_b1 + cq * 4);
    *(float4*)&hbuf[(2 * rp) * 132 + cq * 4] =
        make_float4(acc0[0] + bb.x, acc0[1] + bb.y, acc0[2] + bb.z, acc0[3] + bb.w);
    *(float4*)&hbuf[(2 * rp + 1) * 132 + cq * 4] =
        make_float4(acc1[0] + bb.x, acc1[1] + bb.y, acc1[2] + bb.z, acc1[3] + bb.w);
  }
  __syncthreads();
  // LayerNorm + GELU(exact) + final 128x4
  const int lane = tid & 63;
  const int wq = tid >> 6;
  const float g0c = ln_g[lane], g1c = ln_g[lane + 64];
  const float b0c = ln_b[lane], b1c = ln_b[lane + 64];
  const float4 w2a = *(const float4*)(cls_w2 + lane * 4);
  const float4 w2b = *(const float4*)(cls_w2 + (lane + 64) * 4);
#pragma unroll
  for (int rr = 0; rr < 4; ++rr) {
    const int r = wq * 4 + rr;
    const float x0 = hbuf[r * 132 + lane];
    const float x1 = hbuf[r * 132 + 64 + lane];
    float s = x0 + x1, sq = x0 * x0 + x1 * x1;
#pragma unroll
    for (int m = 32; m >= 1; m >>= 1) {
      s += __shfl_xor(s, m, 64);
      sq += __shfl_xor(sq, m, 64);
    }
    const float mu = s * (1.f / 128.f);
    const float var = sq * (1.f / 128.f) - mu * mu;
    const float rstd = rsqrtf(var + 1e-5f);
    float h0 = (x0 - mu) * rstd * g0c + b0c;
    float h1 = (x1 - mu) * rstd * g1c + b1c;
    h0 = 0.5f * h0 * (1.f + erff(h0 * 0.7071067811865475f));
    h1 = 0.5f * h1 * (1.f + erff(h1 * 0.7071067811865475f));
    float o0 = h0 * w2a.x + h1 * w2b.x;
    float o1 = h0 * w2a.y + h1 * w2b.y;
    float o2 = h0 * w2a.z + h1 * w2b.z;
    float o3 = h0 * w2a.w + h1 * w2b.w;
#pragma unroll
    for (int m = 32; m >= 1; m >>= 1) {
      o0 += __shfl_xor(o0, m, 64);
      o1 += __shfl_xor(o1, m, 64);
      o2 += __shfl_xor(o2, m, 64);
      o3 += __shfl_xor(o3, m, 64);
    }
    if (lane == 0) {
      *(float4*)(out + (size_t)(b0 + r0l + r) * 4) =
          make_float4(o0 + cls_b2[0], o1 + cls_b2[1], o2 + cls_b2[2], o3 + cls_b2[3]);
    }
  }
}

// ================= host =================
extern "C" void kernel_launch(void* const* d_in, const int* in_sizes, int n_in,
                              void* d_out, int out_size, void* d_ws, size_t ws_size,
                              hipStream_t stream) {
  const float* L_norm   = (const float*)d_in[0];
  const float* X_seq    = (const float*)d_in[1];
  const float* conv_w   = (const float*)d_in[2];
  const float* conv_b   = (const float*)d_in[3];
  const float* bn_gamma = (const float*)d_in[4];
  const float* bn_beta  = (const float*)d_in[5];
  const float* bn_mean  = (const float*)d_in[6];
  const float* bn_var   = (const float*)d_in[7];
  const float* gcn1_w   = (const float*)d_in[8];
  const float* gcn1_b   = (const float*)d_in[9];
  const float* mask1    = (const float*)d_in[10];
  const float* gcn2_w   = (const float*)d_in[11];
  const float* gcn2_b   = (const float*)d_in[12];
  const float* mask2    = (const float*)d_in[13];
  const float* beta2    = (const float*)d_in[14];
  const float* attn_w1  = (const float*)d_in[15];
  const float* attn_b1  = (const float*)d_in[16];
  const float* attn_w2  = (const float*)d_in[17];
  const float* attn_b2  = (const float*)d_in[18];
  const float* cls_w1   = (const float*)d_in[19];
  const float* cls_b1   = (const float*)d_in[20];
  const float* ln_gamma = (const float*)d_in[21];
  const float* ln_beta  = (const float*)d_in[22];
  const float* cls_w2   = (const float*)d_in[23];
  const float* cls_b2   = (const float*)d_in[24];

  char* ws = (char*)d_ws;
  float* wsf = (float*)d_ws;
  unsigned int* w1pk = (unsigned int*)(ws + WS_W1PK_B);

  // pick batch chunk that fits the workspace (pots fp16 + ctx fp32 per batch)
  long long avail = (long long)ws_size - (long long)WS_POTS_B;
  long long per = PER_BATCH_POTS_B + PER_BATCH_CTX_B;
  int chunk = 4096;
  if (avail < per * 4096LL) {
    long long c = (avail > 0) ? (avail / per) : 16;
    if (c > 4096) c = 4096;
    c &= ~15LL;
    if (c < 16) c = 16;
    chunk = (int)c;
  }
  unsigned short* pots = (unsigned short*)(ws + WS_POTS_B);
  float* ctx = (float*)(ws + WS_POTS_B + (size_t)chunk * PER_BATCH_POTS_B);

  hipLaunchKernelGGL(k_prep, dim3(1), dim3(256), 0, stream,
                     mask1, mask2, conv_w, conv_b, bn_gamma, bn_beta, bn_mean, bn_var,
                     attn_w1, wsf, w1pk);

  for (int b0 = 0; b0 < 4096; b0 += chunk) {
    int cur = 4096 - b0;
    if (cur > chunk) cur = chunk;
    hipLaunchKernelGGL(k_main, dim3(cur), dim3(256), 0, stream,
                       L_norm, X_seq, gcn1_w, gcn1_b, gcn2_w, gcn2_b, beta2,
                       wsf, pots, b0);
    hipLaunchKernelGGL(k_attn, dim3(cur), dim3(256), 0, stream,
                       pots, w1pk, attn_b1, attn_w2, attn_b2, ctx);
    hipLaunchKernelGGL(k_cls, dim3(cur / 16), dim3(256), 0, stream,
                       ctx, cls_w1, cls_b1, ln_gamma, ln_beta, cls_w2, cls_b2,
                       (float*)d_out, b0);
  }
}

// Round 2
// 747.718 us; speedup vs baseline: 1.6073x; 1.6073x over previous
//
#include <hip/hip_runtime.h>
#include <math.h>

// ---------------- workspace layout ----------------
#define WS_M1_F    0           // 4096 f32
#define WS_M2_F    4096        // 4096 f32
#define WS_BNSC_F  8192        // 64 f32
#define WS_BNSH_F  8256        // 64 f32
#define WS_WT_F    8448        // 12288 f32 (conv_w transposed [ik][o])
#define WS_W1PK_B  83968       // 32768 u32 (attn_w1 packed fp16 pairs [q][k])
#define WS_POTS_B  215040      // pots fp16 [chunk][15][2048]
#define PER_BATCH_POTS_B 61440 // 15*2048*2
#define PER_BATCH_CTX_B  8192  // 2048*4

// ---------------- fp16 helpers ----------------
typedef _Float16 half2v __attribute__((ext_vector_type(2)));
typedef short v8s __attribute__((ext_vector_type(8)));
typedef float v4f __attribute__((ext_vector_type(4)));
typedef float v16f __attribute__((ext_vector_type(16)));

__device__ __forceinline__ unsigned short f2h_u(float x) {
  _Float16 h = (_Float16)x;
  union { _Float16 h; unsigned short u; } v; v.h = h; return v.u;
}
__device__ __forceinline__ float h2f_lo(unsigned int u) {
  union { unsigned short s; _Float16 h; } v; v.s = (unsigned short)(u & 0xffffu); return (float)v.h;
}
__device__ __forceinline__ float h2f_hi(unsigned int u) {
  union { unsigned short s; _Float16 h; } v; v.s = (unsigned short)(u >> 16); return (float)v.h;
}
__device__ __forceinline__ float dot2h(unsigned int a, unsigned int b, float c) {
#if __has_builtin(__builtin_amdgcn_fdot2)
  union { unsigned int u; half2v h; } va, vb; va.u = a; vb.u = b;
  return __builtin_amdgcn_fdot2(va.h, vb.h, c, false);
#else
  return fmaf(h2f_hi(a), h2f_hi(b), fmaf(h2f_lo(a), h2f_lo(b), c));
#endif
}
// bf16 truncation split helpers
__device__ __forceinline__ unsigned short bf16t(float x) {
  union { float f; unsigned int u; } v; v.f = x; return (unsigned short)(v.u >> 16);
}
__device__ __forceinline__ float bf16tof(unsigned short s) {
  union { unsigned int u; float f; } v; v.u = ((unsigned int)s) << 16; return v.f;
}

// ================= K1: prep =================
__global__ __launch_bounds__(256) void k_prep(
    const float* __restrict__ mask1, const float* __restrict__ mask2,
    const float* __restrict__ conv_w, const float* __restrict__ conv_b,
    const float* __restrict__ bn_gamma, const float* __restrict__ bn_beta,
    const float* __restrict__ bn_mean, const float* __restrict__ bn_var,
    const float* __restrict__ attn_w1,
    float* __restrict__ wsf, unsigned int* __restrict__ w1pk)
{
  const int tid = threadIdx.x;
  float* m1 = wsf + WS_M1_F;
  float* m2 = wsf + WS_M2_F;
  float* bnsc = wsf + WS_BNSC_F;
  float* bnsh = wsf + WS_BNSH_F;
  float* wT = wsf + WS_WT_F;
  for (int e = tid; e < 4096; e += 256) {
    int i = e >> 6, j = e & 63;
    float s1 = mask1[e] + mask1[j * 64 + i];
    float s2 = mask2[e] + mask2[j * 64 + i];
    m1[e] = 0.5f / (1.f + expf(-s1));
    m2[e] = 0.5f / (1.f + expf(-s2));
  }
  if (tid < 64) {
    float sc = bn_gamma[tid] * rsqrtf(bn_var[tid] + 1e-5f);
    bnsc[tid] = sc;
    bnsh[tid] = (conv_b[tid] - bn_mean[tid]) * sc + bn_beta[tid];
  }
  for (int e = tid; e < 12288; e += 256) {
    int o = e / 192, ik = e % 192;
    wT[ik * 64 + o] = conv_w[e];
  }
  for (int e = tid; e < 32768; e += 256) {
    int q = e >> 5, k = e & 31;
    unsigned int lo = f2h_u(attn_w1[(2 * q) * 32 + k]);
    unsigned int hi = f2h_u(attn_w1[(2 * q + 1) * 32 + k]);
    w1pk[e] = lo | (hi << 16);
  }
}

// ================= K2: recurrence (one block per batch), MFMA version =================
__global__ __launch_bounds__(256) void k_main(
    const float* __restrict__ L_norm, const float* __restrict__ X_seq,
    const float* __restrict__ gcn1_w, const float* __restrict__ gcn1_b,
    const float* __restrict__ gcn2_w, const float* __restrict__ gcn2_b,
    const float* __restrict__ beta2p,
    const float* __restrict__ wsf, unsigned short* __restrict__ pots,
    int b0)
{
  __shared__ float xraw[960];                        // X_seq[b] [t][n]
  __shared__ float xcur[960];                        // conv+bn output [t][o]
  __shared__ float zp[4 * 64];                       // z1 partials [q][n]
  __shared__ __align__(16) unsigned short spk1T[16 * 72]; // spk1^T bf16 [c][j], row stride 72 u16
  __shared__ __align__(16) float Z2f[64 * 20];       // Z2 fp32 [i][c], row stride 20

  const int tid = threadIdx.x;
  const int lane = tid & 63;
  const int wv = tid >> 6;
  const int b = b0 + blockIdx.x;

  const float* m1 = wsf + WS_M1_F;
  const float* m2 = wsf + WS_M2_F;
  const float* bnsc = wsf + WS_BNSC_F;
  const float* bnsh = wsf + WS_BNSH_F;
  const float* wT = wsf + WS_WT_F;

  // stage X_seq[b]
  for (int e = tid; e < 960; e += 256) xraw[e] = X_seq[(size_t)b * 960 + e];

  // ---- L1 quarter in registers: wave wv holds L1[lane][16wv..16wv+15] ----
  float L1q[16];
  {
    const float* Lb = L_norm + (size_t)b * 4096 + lane * 64 + wv * 16;
    const float* mr = m1 + lane * 64 + wv * 16;
#pragma unroll
    for (int q4 = 0; q4 < 4; ++q4) {
      float4 lv = *(const float4*)(Lb + 4 * q4);
      float4 mv = *(const float4*)(mr + 4 * q4);
      L1q[4 * q4 + 0] = lv.x * mv.x;
      L1q[4 * q4 + 1] = lv.y * mv.y;
      L1q[4 * q4 + 2] = lv.z * mv.z;
      L1q[4 * q4 + 3] = lv.w * mv.w;
    }
  }

  // ---- Stage-A A-fragments: L2 tile rows [16wv,16wv+16), hi/lo bf16 split ----
  // 16x16x32 A layout: A[m=lane&15][k=(lane>>4)*8+e], k-block kb adds 32.
  v8s A_hi[2], A_lo[2];
  {
    const int irow = wv * 16 + (lane & 15);
    const int quad = (lane >> 4) & 3;
#pragma unroll
    for (int kb = 0; kb < 2; ++kb) {
      const float* Lb = L_norm + (size_t)b * 4096 + irow * 64 + kb * 32 + quad * 8;
      const float* mr = m2 + irow * 64 + kb * 32 + quad * 8;
      float4 la = *(const float4*)Lb, lb2 = *(const float4*)(Lb + 4);
      float4 ma = *(const float4*)mr, mb = *(const float4*)(mr + 4);
      float v[8] = { la.x * ma.x, la.y * ma.y, la.z * ma.z, la.w * ma.w,
                     lb2.x * mb.x, lb2.y * mb.y, lb2.z * mb.z, lb2.w * mb.w };
#pragma unroll
      for (int e = 0; e < 8; ++e) {
        unsigned short h = bf16t(v[e]);
        unsigned short l = bf16t(v[e] - bf16tof(h));
        A_hi[kb][e] = (short)h;
        A_lo[kb][e] = (short)l;
      }
    }
  }

  // ---- Stage-B B-fragments: W2 hi/lo (constant) ----
  // 32x32x16 B layout: B[k=(lane>>5)*8+e][n=lane&31]
  v8s W_hi, W_lo;
  {
    const int n = lane & 31;
    const int kh = (lane >> 5) & 1;
#pragma unroll
    for (int e = 0; e < 8; ++e) {
      float x = gcn2_w[(kh * 8 + e) * 32 + n];
      unsigned short h = bf16t(x);
      unsigned short l = bf16t(x - bf16tof(h));
      W_hi[e] = (short)h;
      W_lo[e] = (short)l;
    }
  }

  // per-thread constants
  const float b2h = gcn2_b[lane & 31];
  const int np = tid >> 3;      // node-pair 0..31
  const int cp = tid & 7;       // channel-pair 0..7
  float w1c[2], b1c[2];
#pragma unroll
  for (int d = 0; d < 2; ++d) { w1c[d] = gcn1_w[2 * cp + d]; b1c[d] = gcn1_b[2 * cp + d]; }
  const float beta2 = beta2p[0];

  __syncthreads();

  // ---- causal conv1d + BN -> xcur[t][o]; wave wv handles t = wv, wv+4, wv+8, wv+12 ----
  {
    const int o = lane;
    const int t0 = wv, t1 = wv + 4, t2 = wv + 8, t3 = wv + 12;
    float a0 = 0.f, a1 = 0.f, a2 = 0.f, a3 = 0.f;
    for (int i = 0; i < 64; ++i) {
      const float w0 = wT[(3 * i + 0) * 64 + o];
      const float w1 = wT[(3 * i + 1) * 64 + o];
      const float w2 = wT[(3 * i + 2) * 64 + o];
      float xa = (t0 >= 2) ? xraw[(t0 - 2) * 64 + i] : 0.f;
      float xb = (t0 >= 1) ? xraw[(t0 - 1) * 64 + i] : 0.f;
      a0 += w0 * xa + w1 * xb + w2 * xraw[t0 * 64 + i];
      a1 += w0 * xraw[(t1 - 2) * 64 + i] + w1 * xraw[(t1 - 1) * 64 + i] + w2 * xraw[t1 * 64 + i];
      a2 += w0 * xraw[(t2 - 2) * 64 + i] + w1 * xraw[(t2 - 1) * 64 + i] + w2 * xraw[t2 * 64 + i];
      if (t3 < 15)
        a3 += w0 * xraw[(t3 - 2) * 64 + i] + w1 * xraw[(t3 - 1) * 64 + i] + w2 * xraw[t3 * 64 + i];
    }
    const float sc = bnsc[o], sh = bnsh[o];
    xcur[t0 * 64 + o] = a0 * sc + sh;
    xcur[t1 * 64 + o] = a1 * sc + sh;
    xcur[t2 * 64 + o] = a2 * sc + sh;
    if (t3 < 15) xcur[t3 * 64 + o] = a3 * sc + sh;
  }

  float mem_t = 0.f;                      // redundant per wave (lane = node)
  float mg1[4] = {0.f, 0.f, 0.f, 0.f};    // layer-1 state: [d*2+e] for c=2cp+d, n=2np+e
  v16f mg2;                               // layer-2 state in 32x32x16 C layout (waves 0,1)
#pragma unroll
  for (int r = 0; r < 16; ++r) mg2[r] = 0.f;

  unsigned short* pbase = pots + (size_t)blockIdx.x * 30720 + (lane & 31);

  __syncthreads();

  for (int t = 0; t < 15; ++t) {
    // ---- P1: input LIF (all waves redundant) + z1 quarter via readlane ----
    {
      float xc = xcur[t * 64 + lane];
      float rs = (mem_t > 1.f) ? 1.f : 0.f;
      mem_t = 0.9f * mem_t + xc - rs;
      float sp = (mem_t > 1.f) ? 1.f : 0.f;
      int spi = __float_as_int(sp);
      float zq = 0.f;
#pragma unroll
      for (int k = 0; k < 16; ++k) {
        float s = __int_as_float(__builtin_amdgcn_readlane(spi, wv * 16 + k));
        zq = fmaf(s, L1q[k], zq);
      }
      zp[wv * 64 + lane] = zq;
    }
    __syncthreads();
    // ---- P2: layer-1 LIF, write spk1^T as bf16 bits (u32 node-pairs) ----
    {
      float2 q0 = *(const float2*)&zp[0 * 64 + 2 * np];
      float2 q1 = *(const float2*)&zp[1 * 64 + 2 * np];
      float2 q2 = *(const float2*)&zp[2 * 64 + 2 * np];
      float2 q3 = *(const float2*)&zp[3 * 64 + 2 * np];
      float z0 = q0.x + q1.x + q2.x + q3.x;
      float z1v = q0.y + q1.y + q2.y + q3.y;
#pragma unroll
      for (int d = 0; d < 2; ++d) {
        float cur0 = fmaf(z0, w1c[d], b1c[d]);
        float rs0 = (mg1[d * 2 + 0] > 1.f) ? 1.f : 0.f;
        mg1[d * 2 + 0] = 0.85f * mg1[d * 2 + 0] + cur0 - rs0;
        unsigned int bits0 = (mg1[d * 2 + 0] > 1.f) ? 0x3F80u : 0u;
        float cur1 = fmaf(z1v, w1c[d], b1c[d]);
        float rs1 = (mg1[d * 2 + 1] > 1.f) ? 1.f : 0.f;
        mg1[d * 2 + 1] = 0.85f * mg1[d * 2 + 1] + cur1 - rs1;
        unsigned int bits1 = (mg1[d * 2 + 1] > 1.f) ? 0x3F80u : 0u;
        *(unsigned int*)&spk1T[(2 * cp + d) * 72 + 2 * np] = bits0 | (bits1 << 16);
      }
    }
    __syncthreads();
    // ---- Stage A: Z2 = L2 @ spk1 via 16x16x32 bf16 MFMA (exact binary B) ----
    {
      const int c = lane & 15;
      const int quad = (lane >> 4) & 3;
      const unsigned short* bp = spk1T + c * 72 + quad * 8;
      v8s B0 = *(const v8s*)(bp);
      v8s B1 = *(const v8s*)(bp + 32);
      v4f acc = {0.f, 0.f, 0.f, 0.f};
      acc = __builtin_amdgcn_mfma_f32_16x16x32_bf16(A_hi[0], B0, acc, 0, 0, 0);
      acc = __builtin_amdgcn_mfma_f32_16x16x32_bf16(A_lo[0], B0, acc, 0, 0, 0);
      acc = __builtin_amdgcn_mfma_f32_16x16x32_bf16(A_hi[1], B1, acc, 0, 0, 0);
      acc = __builtin_amdgcn_mfma_f32_16x16x32_bf16(A_lo[1], B1, acc, 0, 0, 0);
      const int r0 = wv * 16 + quad * 4;
#pragma unroll
      for (int r = 0; r < 4; ++r) Z2f[(r0 + r) * 20 + c] = acc[r];
    }
    __syncthreads();
    // ---- Stage B: cur2 = Z2 @ W2 via 32x32x16 bf16 MFMA; LIF2; pots store ----
    if (wv < 2) {
      const int m = lane & 31;
      const int half = lane >> 5;
      const float* zr = Z2f + (wv * 32 + m) * 20 + half * 8;
      float4 za = *(const float4*)zr;
      float4 zb = *(const float4*)(zr + 4);
      float vv[8] = {za.x, za.y, za.z, za.w, zb.x, zb.y, zb.z, zb.w};
      v8s Ah, Al;
#pragma unroll
      for (int e = 0; e < 8; ++e) {
        unsigned short h = bf16t(vv[e]);
        unsigned short l = bf16t(vv[e] - bf16tof(h));
        Ah[e] = (short)h;
        Al[e] = (short)l;
      }
      v16f acc;
#pragma unroll
      for (int r = 0; r < 16; ++r) {
        float rs = (mg2[r] > 1.f) ? 1.f : 0.f;
        acc[r] = fmaf(beta2, mg2[r], b2h - rs);
      }
      acc = __builtin_amdgcn_mfma_f32_32x32x16_bf16(Ah, W_hi, acc, 0, 0, 0);
      acc = __builtin_amdgcn_mfma_f32_32x32x16_bf16(Al, W_hi, acc, 0, 0, 0);
      acc = __builtin_amdgcn_mfma_f32_32x32x16_bf16(Ah, W_lo, acc, 0, 0, 0);
      mg2 = acc;
      unsigned short* pb = pbase + (size_t)t * 2048;
#pragma unroll
      for (int r = 0; r < 16; ++r) {
        int i = wv * 32 + (r & 3) + 8 * (r >> 2) + 4 * half;
        pb[i * 32] = f2h_u(acc[r]);
      }
    }
    // loop-around is safe: zp next written after 2 barriers, spk1T after bar3+bar1',
    // Z2f after bar1'+bar2'.
  }
}

// ================= K3: attention (one block per batch) =================
__global__ __launch_bounds__(256) void k_attn(
    const unsigned short* __restrict__ pots,
    const unsigned int* __restrict__ w1pk,
    const float* __restrict__ attn_b1, const float* __restrict__ attn_w2,
    const float* __restrict__ attn_b2,
    float* __restrict__ ctx)
{
  __shared__ unsigned int potsu[15 * 512];
  __shared__ float red[15 * 256];
  __shared__ float scores[16];
  const int tid = threadIdx.x;
  const int k = tid & 31;
  const int g = tid >> 5;
  const unsigned int* pg = (const unsigned int*)pots + (size_t)blockIdx.x * 15360;

  float p[15];
#pragma unroll
  for (int t = 0; t < 15; ++t) p[t] = 0.f;

  for (int s = 0; s < 2; ++s) {
    for (int e = tid; e < 7680; e += 256) {
      int t = e >> 9, q = e & 511;
      potsu[e] = pg[t * 1024 + s * 512 + q];
    }
    __syncthreads();
    const unsigned int* wp = w1pk + (size_t)(s * 512 + g * 64) * 32 + k;
#pragma unroll 4
    for (int j = 0; j < 64; ++j) {
      const unsigned int wvp = wp[j * 32];
#pragma unroll
      for (int t = 0; t < 15; ++t) {
        p[t] = dot2h(potsu[t * 512 + g * 64 + j], wvp, p[t]);
      }
    }
    __syncthreads();
  }
#pragma unroll
  for (int t = 0; t < 15; ++t) red[t * 256 + tid] = p[t];
  __syncthreads();
  {
    const float b1k = attn_b1[k];
    const float w2k = attn_w2[k];
    float vA = b1k;
#pragma unroll
    for (int gg = 0; gg < 8; ++gg) vA += red[g * 256 + gg * 32 + k];
    float sA = tanhf(vA) * w2k;
    float sB = 0.f;
    const int tb = g + 8;
    if (tb < 15) {
      float vB = b1k;
#pragma unroll
      for (int gg = 0; gg < 8; ++gg) vB += red[tb * 256 + gg * 32 + k];
      sB = tanhf(vB) * w2k;
    }
#pragma unroll
    for (int m = 16; m >= 1; m >>= 1) {
      sA += __shfl_xor(sA, m, 64);
      sB += __shfl_xor(sB, m, 64);
    }
    if (k == 0) {
      scores[g] = sA + attn_b2[0];
      if (tb < 15) scores[tb] = sB + attn_b2[0];
    }
  }
  __syncthreads();
  float wt[15];
  float mx = scores[0];
#pragma unroll
  for (int t = 1; t < 15; ++t) mx = fmaxf(mx, scores[t]);
  float den = 0.f;
#pragma unroll
  for (int t = 0; t < 15; ++t) { wt[t] = expf(scores[t] - mx); den += wt[t]; }
  const float inv = 1.f / den;
  float c8[8] = {0.f, 0.f, 0.f, 0.f, 0.f, 0.f, 0.f, 0.f};
  const unsigned short* pp = pots + (size_t)blockIdx.x * 30720 + tid * 8;
  for (int t = 0; t < 15; ++t) {
    uint4 u = *(const uint4*)(pp + (size_t)t * 2048);
    const float w = wt[t] * inv;
    c8[0] += w * h2f_lo(u.x); c8[1] += w * h2f_hi(u.x);
    c8[2] += w * h2f_lo(u.y); c8[3] += w * h2f_hi(u.y);
    c8[4] += w * h2f_lo(u.z); c8[5] += w * h2f_hi(u.z);
    c8[6] += w * h2f_lo(u.w); c8[7] += w * h2f_hi(u.w);
  }
  float* cb = ctx + (size_t)blockIdx.x * 2048 + tid * 8;
  *(float4*)cb = make_float4(c8[0], c8[1], c8[2], c8[3]);
  *(float4*)(cb + 4) = make_float4(c8[4], c8[5], c8[6], c8[7]);
}

// ================= K4: classifier (16 rows per block) =================
__global__ __launch_bounds__(256) void k_cls(
    const float* __restrict__ ctx,
    const float* __restrict__ cls_w1, const float* __restrict__ cls_b1,
    const float* __restrict__ ln_g, const float* __restrict__ ln_b,
    const float* __restrict__ cls_w2, const float* __restrict__ cls_b2,
    float* __restrict__ out, int b0)
{
  __shared__ float Ach[16 * 65];
  __shared__ float Bch[64 * 132];
  __shared__ float hbuf[16 * 132];
  const int tid = threadIdx.x;
  const int rp = tid & 7;
  const int cq = tid >> 3;
  const int r0l = blockIdx.x * 16;

  float acc0[4] = {0.f, 0.f, 0.f, 0.f};
  float acc1[4] = {0.f, 0.f, 0.f, 0.f};
  for (int kc = 0; kc < 2048; kc += 64) {
    {
      int f = tid * 4;
      int r = f >> 6, kk = f & 63;
      float4 v = *(const float4*)(ctx + (size_t)(r0l + r) * 2048 + kc + kk);
      Ach[r * 65 + kk + 0] = v.x;
      Ach[r * 65 + kk + 1] = v.y;
      Ach[r * 65 + kk + 2] = v.z;
      Ach[r * 65 + kk + 3] = v.w;
    }
#pragma unroll
    for (int q = 0; q < 8; ++q) {
      int f = tid * 4 + q * 1024;
      int kk = f >> 7, c = f & 127;
      float4 v = *(const float4*)(cls_w1 + (size_t)(kc + kk) * 128 + c);
      *(float4*)&Bch[kk * 132 + c] = v;
    }
    __syncthreads();
#pragma unroll 8
    for (int kk = 0; kk < 64; ++kk) {
      const float a0 = Ach[(2 * rp) * 65 + kk];
      const float a1 = Ach[(2 * rp + 1) * 65 + kk];
      const float4 bv = *(const float4*)&Bch[kk * 132 + cq * 4];
      acc0[0] = fmaf(a0, bv.x, acc0[0]); acc0[1] = fmaf(a0, bv.y, acc0[1]);
      acc0[2] = fmaf(a0, bv.z, acc0[2]); acc0[3] = fmaf(a0, bv.w, acc0[3]);
      acc1[0] = fmaf(a1, bv.x, acc1[0]); acc1[1] = fmaf(a1, bv.y, acc1[1]);
      acc1[2] = fmaf(a1, bv.z, acc1[2]); acc1[3] = fmaf(a1, bv.w, acc1[3]);
    }
    __syncthreads();
  }
  {
    const float4 bb = *(const float4*)(cls_b1 + cq * 4);
    *(float4*)&hbuf[(2 * rp) * 132 + cq * 4] =
        make_float4(acc0[0] + bb.x, acc0[1] + bb.y, acc0[2] + bb.z, acc0[3] + bb.w);
    *(float4*)&hbuf[(2 * rp + 1) * 132 + cq * 4] =
        make_float4(acc1[0] + bb.x, acc1[1] + bb.y, acc1[2] + bb.z, acc1[3] + bb.w);
  }
  __syncthreads();
  const int lane = tid & 63;
  const int wq = tid >> 6;
  const float g0c = ln_g[lane], g1c = ln_g[lane + 64];
  const float b0c = ln_b[lane], b1c = ln_b[lane + 64];
  const float4 w2a = *(const float4*)(cls_w2 + lane * 4);
  const float4 w2b = *(const float4*)(cls_w2 + (lane + 64) * 4);
#pragma unroll
  for (int rr = 0; rr < 4; ++rr) {
    const int r = wq * 4 + rr;
    const float x0 = hbuf[r * 132 + lane];
    const float x1 = hbuf[r * 132 + 64 + lane];
    float s = x0 + x1, sq = x0 * x0 + x1 * x1;
#pragma unroll
    for (int m = 32; m >= 1; m >>= 1) {
      s += __shfl_xor(s, m, 64);
      sq += __shfl_xor(sq, m, 64);
    }
    const float mu = s * (1.f / 128.f);
    const float var = sq * (1.f / 128.f) - mu * mu;
    const float rstd = rsqrtf(var + 1e-5f);
    float h0 = (x0 - mu) * rstd * g0c + b0c;
    float h1 = (x1 - mu) * rstd * g1c + b1c;
    h0 = 0.5f * h0 * (1.f + erff(h0 * 0.7071067811865475f));
    h1 = 0.5f * h1 * (1.f + erff(h1 * 0.7071067811865475f));
    float o0 = h0 * w2a.x + h1 * w2b.x;
    float o1 = h0 * w2a.y + h1 * w2b.y;
    float o2 = h0 * w2a.z + h1 * w2b.z;
    float o3 = h0 * w2a.w + h1 * w2b.w;
#pragma unroll
    for (int m = 32; m >= 1; m >>= 1) {
      o0 += __shfl_xor(o0, m, 64);
      o1 += __shfl_xor(o1, m, 64);
      o2 += __shfl_xor(o2, m, 64);
      o3 += __shfl_xor(o3, m, 64);
    }
    if (lane == 0) {
      *(float4*)(out + (size_t)(b0 + r0l + r) * 4) =
          make_float4(o0 + cls_b2[0], o1 + cls_b2[1], o2 + cls_b2[2], o3 + cls_b2[3]);
    }
  }
}

// ================= host =================
extern "C" void kernel_launch(void* const* d_in, const int* in_sizes, int n_in,
                              void* d_out, int out_size, void* d_ws, size_t ws_size,
                              hipStream_t stream) {
  const float* L_norm   = (const float*)d_in[0];
  const float* X_seq    = (const float*)d_in[1];
  const float* conv_w   = (const float*)d_in[2];
  const float* conv_b   = (const float*)d_in[3];
  const float* bn_gamma = (const float*)d_in[4];
  const float* bn_beta  = (const float*)d_in[5];
  const float* bn_mean  = (const float*)d_in[6];
  const float* bn_var   = (const float*)d_in[7];
  const float* gcn1_w   = (const float*)d_in[8];
  const float* gcn1_b   = (const float*)d_in[9];
  const float* mask1    = (const float*)d_in[10];
  const float* gcn2_w   = (const float*)d_in[11];
  const float* gcn2_b   = (const float*)d_in[12];
  const float* mask2    = (const float*)d_in[13];
  const float* beta2    = (const float*)d_in[14];
  const float* attn_w1  = (const float*)d_in[15];
  const float* attn_b1  = (const float*)d_in[16];
  const float* attn_w2  = (const float*)d_in[17];
  const float* attn_b2  = (const float*)d_in[18];
  const float* cls_w1   = (const float*)d_in[19];
  const float* cls_b1   = (const float*)d_in[20];
  const float* ln_gamma = (const float*)d_in[21];
  const float* ln_beta  = (const float*)d_in[22];
  const float* cls_w2   = (const float*)d_in[23];
  const float* cls_b2   = (const float*)d_in[24];

  char* ws = (char*)d_ws;
  float* wsf = (float*)d_ws;
  unsigned int* w1pk = (unsigned int*)(ws + WS_W1PK_B);

  long long avail = (long long)ws_size - (long long)WS_POTS_B;
  long long per = PER_BATCH_POTS_B + PER_BATCH_CTX_B;
  int chunk = 4096;
  if (avail < per * 4096LL) {
    long long c = (avail > 0) ? (avail / per) : 16;
    if (c > 4096) c = 4096;
    c &= ~15LL;
    if (c < 16) c = 16;
    chunk = (int)c;
  }
  unsigned short* pots = (unsigned short*)(ws + WS_POTS_B);
  float* ctx = (float*)(ws + WS_POTS_B + (size_t)chunk * PER_BATCH_POTS_B);

  hipLaunchKernelGGL(k_prep, dim3(1), dim3(256), 0, stream,
                     mask1, mask2, conv_w, conv_b, bn_gamma, bn_beta, bn_mean, bn_var,
                     attn_w1, wsf, w1pk);

  for (int b0 = 0; b0 < 4096; b0 += chunk) {
    int cur = 4096 - b0;
    if (cur > chunk) cur = chunk;
    hipLaunchKernelGGL(k_main, dim3(cur), dim3(256), 0, stream,
                       L_norm, X_seq, gcn1_w, gcn1_b, gcn2_w, gcn2_b, beta2,
                       wsf, pots, b0);
    hipLaunchKernelGGL(k_attn, dim3(cur), dim3(256), 0, stream,
                       pots, w1pk, attn_b1, attn_w2, attn_b2, ctx);
    hipLaunchKernelGGL(k_cls, dim3(cur / 16), dim3(256), 0, stream,
                       ctx, cls_w1, cls_b1, ln_gamma, ln_beta, cls_w2, cls_b2,
                       (float*)d_out, b0);
  }
}

// Round 3
// 609.377 us; speedup vs baseline: 1.9722x; 1.2270x over previous
//
#include <hip/hip_runtime.h>
#include <math.h>

// ---------------- workspace layout (bytes unless _F) ----------------
#define WS_M1_F    0           // 4096 f32
#define WS_M2_F    4096        // 4096 f32
#define WS_BNSC_F  8192        // 64 f32
#define WS_BNSH_F  8256        // 64 f32
#define WS_WT_F    8448        // 12288 f32 (conv_w transposed [ik][o])
#define OFF_W1T    83968       // u16[32*2048]  attn_w1^T fp16  -> +131072 = 215040
#define OFF_CW1H   215040      // u16[128*2048] cls_w1^T bf16-hi -> +524288 = 739328
#define OFF_CW1L   739328      // u16[128*2048] cls_w1^T bf16-lo -> +524288 = 1263616
#define OFF_DYN    1263616     // pots fp16 [chunk][15][2048], then ctx hi/lo planes
#define PER_BATCH_POTS_B 61440 // 15*2048*2
#define PER_BATCH_CTX_B  8192  // 2048*2 *2 planes

typedef _Float16 half2v __attribute__((ext_vector_type(2)));
typedef _Float16 v8h __attribute__((ext_vector_type(8)));
typedef short v8s __attribute__((ext_vector_type(8)));
typedef float v4f __attribute__((ext_vector_type(4)));
typedef float v16f __attribute__((ext_vector_type(16)));

__device__ __forceinline__ unsigned short f2h_u(float x) {
  _Float16 h = (_Float16)x;
  union { _Float16 h; unsigned short u; } v; v.h = h; return v.u;
}
// bf16 truncation split helpers
__device__ __forceinline__ unsigned short bf16t(float x) {
  union { float f; unsigned int u; } v; v.f = x; return (unsigned short)(v.u >> 16);
}
__device__ __forceinline__ float bf16tof(unsigned short s) {
  union { unsigned int u; float f; } v; v.u = ((unsigned int)s) << 16; return v.f;
}

// ================= K1: prep (multi-block) =================
__global__ __launch_bounds__(256) void k_prep(
    const float* __restrict__ mask1, const float* __restrict__ mask2,
    const float* __restrict__ conv_w, const float* __restrict__ conv_b,
    const float* __restrict__ bn_gamma, const float* __restrict__ bn_beta,
    const float* __restrict__ bn_mean, const float* __restrict__ bn_var,
    const float* __restrict__ attn_w1, const float* __restrict__ cls_w1,
    float* __restrict__ wsf, unsigned short* __restrict__ w1t,
    unsigned short* __restrict__ cw1h, unsigned short* __restrict__ cw1l)
{
  const int gid = blockIdx.x * 256 + threadIdx.x;
  const int gsz = gridDim.x * 256;
  float* m1 = wsf + WS_M1_F;
  float* m2 = wsf + WS_M2_F;
  float* bnsc = wsf + WS_BNSC_F;
  float* bnsh = wsf + WS_BNSH_F;
  float* wT = wsf + WS_WT_F;
  for (int e = gid; e < 4096; e += gsz) {
    int i = e >> 6, j = e & 63;
    float s1 = mask1[e] + mask1[j * 64 + i];
    float s2 = mask2[e] + mask2[j * 64 + i];
    m1[e] = 0.5f / (1.f + expf(-s1));
    m2[e] = 0.5f / (1.f + expf(-s2));
  }
  for (int e = gid; e < 64; e += gsz) {
    float sc = bn_gamma[e] * rsqrtf(bn_var[e] + 1e-5f);
    bnsc[e] = sc;
    bnsh[e] = (conv_b[e] - bn_mean[e]) * sc + bn_beta[e];
  }
  for (int e = gid; e < 12288; e += gsz) {
    int o = e / 192, ik = e % 192;
    wT[ik * 64 + o] = conv_w[e];
  }
  // attn_w1^T fp16: w1t[n][i] = attn_w1[i][n]
  for (int e = gid; e < 65536; e += gsz) {
    int n = e >> 11, i = e & 2047;
    w1t[e] = f2h_u(attn_w1[i * 32 + n]);
  }
  // cls_w1^T bf16 hi/lo planes: cw1[n][k]
  for (int e = gid; e < 262144; e += gsz) {
    int n = e >> 11, k = e & 2047;
    float x = cls_w1[k * 128 + n];
    unsigned short h = bf16t(x);
    cw1h[e] = h;
    cw1l[e] = bf16t(x - bf16tof(h));
  }
}

// ================= K2: recurrence (one block per batch), MFMA version =================
__global__ __launch_bounds__(256) void k_main(
    const float* __restrict__ L_norm, const float* __restrict__ X_seq,
    const float* __restrict__ gcn1_w, const float* __restrict__ gcn1_b,
    const float* __restrict__ gcn2_w, const float* __restrict__ gcn2_b,
    const float* __restrict__ beta2p,
    const float* __restrict__ wsf, unsigned short* __restrict__ pots,
    int b0)
{
  __shared__ float xraw[960];
  __shared__ float xcur[960];
  __shared__ float zp[4 * 64];
  __shared__ __align__(16) unsigned short spk1T[16 * 72];
  __shared__ __align__(16) float Z2f[64 * 20];

  const int tid = threadIdx.x;
  const int lane = tid & 63;
  const int wv = tid >> 6;
  const int b = b0 + blockIdx.x;

  const float* m1 = wsf + WS_M1_F;
  const float* m2 = wsf + WS_M2_F;
  const float* bnsc = wsf + WS_BNSC_F;
  const float* bnsh = wsf + WS_BNSH_F;
  const float* wT = wsf + WS_WT_F;

  for (int e = tid; e < 960; e += 256) xraw[e] = X_seq[(size_t)b * 960 + e];

  float L1q[16];
  {
    const float* Lb = L_norm + (size_t)b * 4096 + lane * 64 + wv * 16;
    const float* mr = m1 + lane * 64 + wv * 16;
#pragma unroll
    for (int q4 = 0; q4 < 4; ++q4) {
      float4 lv = *(const float4*)(Lb + 4 * q4);
      float4 mv = *(const float4*)(mr + 4 * q4);
      L1q[4 * q4 + 0] = lv.x * mv.x;
      L1q[4 * q4 + 1] = lv.y * mv.y;
      L1q[4 * q4 + 2] = lv.z * mv.z;
      L1q[4 * q4 + 3] = lv.w * mv.w;
    }
  }

  v8s A_hi[2], A_lo[2];
  {
    const int irow = wv * 16 + (lane & 15);
    const int quad = (lane >> 4) & 3;
#pragma unroll
    for (int kb = 0; kb < 2; ++kb) {
      const float* Lb = L_norm + (size_t)b * 4096 + irow * 64 + kb * 32 + quad * 8;
      const float* mr = m2 + irow * 64 + kb * 32 + quad * 8;
      float4 la = *(const float4*)Lb, lb2 = *(const float4*)(Lb + 4);
      float4 ma = *(const float4*)mr, mb = *(const float4*)(mr + 4);
      float v[8] = { la.x * ma.x, la.y * ma.y, la.z * ma.z, la.w * ma.w,
                     lb2.x * mb.x, lb2.y * mb.y, lb2.z * mb.z, lb2.w * mb.w };
#pragma unroll
      for (int e = 0; e < 8; ++e) {
        unsigned short h = bf16t(v[e]);
        unsigned short l = bf16t(v[e] - bf16tof(h));
        A_hi[kb][e] = (short)h;
        A_lo[kb][e] = (short)l;
      }
    }
  }

  v8s W_hi, W_lo;
  {
    const int n = lane & 31;
    const int kh = (lane >> 5) & 1;
#pragma unroll
    for (int e = 0; e < 8; ++e) {
      float x = gcn2_w[(kh * 8 + e) * 32 + n];
      unsigned short h = bf16t(x);
      unsigned short l = bf16t(x - bf16tof(h));
      W_hi[e] = (short)h;
      W_lo[e] = (short)l;
    }
  }

  const float b2h = gcn2_b[lane & 31];
  const int np = tid >> 3;
  const int cp = tid & 7;
  float w1c[2], b1c[2];
#pragma unroll
  for (int d = 0; d < 2; ++d) { w1c[d] = gcn1_w[2 * cp + d]; b1c[d] = gcn1_b[2 * cp + d]; }
  const float beta2 = beta2p[0];

  __syncthreads();

  {
    const int o = lane;
    const int t0 = wv, t1 = wv + 4, t2 = wv + 8, t3 = wv + 12;
    float a0 = 0.f, a1 = 0.f, a2 = 0.f, a3 = 0.f;
    for (int i = 0; i < 64; ++i) {
      const float w0 = wT[(3 * i + 0) * 64 + o];
      const float w1 = wT[(3 * i + 1) * 64 + o];
      const float w2 = wT[(3 * i + 2) * 64 + o];
      float xa = (t0 >= 2) ? xraw[(t0 - 2) * 64 + i] : 0.f;
      float xb = (t0 >= 1) ? xraw[(t0 - 1) * 64 + i] : 0.f;
      a0 += w0 * xa + w1 * xb + w2 * xraw[t0 * 64 + i];
      a1 += w0 * xraw[(t1 - 2) * 64 + i] + w1 * xraw[(t1 - 1) * 64 + i] + w2 * xraw[t1 * 64 + i];
      a2 += w0 * xraw[(t2 - 2) * 64 + i] + w1 * xraw[(t2 - 1) * 64 + i] + w2 * xraw[t2 * 64 + i];
      if (t3 < 15)
        a3 += w0 * xraw[(t3 - 2) * 64 + i] + w1 * xraw[(t3 - 1) * 64 + i] + w2 * xraw[t3 * 64 + i];
    }
    const float sc = bnsc[o], sh = bnsh[o];
    xcur[t0 * 64 + o] = a0 * sc + sh;
    xcur[t1 * 64 + o] = a1 * sc + sh;
    xcur[t2 * 64 + o] = a2 * sc + sh;
    if (t3 < 15) xcur[t3 * 64 + o] = a3 * sc + sh;
  }

  float mem_t = 0.f;
  float mg1[4] = {0.f, 0.f, 0.f, 0.f};
  v16f mg2;
#pragma unroll
  for (int r = 0; r < 16; ++r) mg2[r] = 0.f;

  unsigned short* pbase = pots + (size_t)blockIdx.x * 30720 + (lane & 31);

  __syncthreads();

  for (int t = 0; t < 15; ++t) {
    {
      float xc = xcur[t * 64 + lane];
      float rs = (mem_t > 1.f) ? 1.f : 0.f;
      mem_t = 0.9f * mem_t + xc - rs;
      float sp = (mem_t > 1.f) ? 1.f : 0.f;
      int spi = __float_as_int(sp);
      float zq = 0.f;
#pragma unroll
      for (int k = 0; k < 16; ++k) {
        float s = __int_as_float(__builtin_amdgcn_readlane(spi, wv * 16 + k));
        zq = fmaf(s, L1q[k], zq);
      }
      zp[wv * 64 + lane] = zq;
    }
    __syncthreads();
    {
      float2 q0 = *(const float2*)&zp[0 * 64 + 2 * np];
      float2 q1 = *(const float2*)&zp[1 * 64 + 2 * np];
      float2 q2 = *(const float2*)&zp[2 * 64 + 2 * np];
      float2 q3 = *(const float2*)&zp[3 * 64 + 2 * np];
      float z0 = q0.x + q1.x + q2.x + q3.x;
      float z1v = q0.y + q1.y + q2.y + q3.y;
#pragma unroll
      for (int d = 0; d < 2; ++d) {
        float cur0 = fmaf(z0, w1c[d], b1c[d]);
        float rs0 = (mg1[d * 2 + 0] > 1.f) ? 1.f : 0.f;
        mg1[d * 2 + 0] = 0.85f * mg1[d * 2 + 0] + cur0 - rs0;
        unsigned int bits0 = (mg1[d * 2 + 0] > 1.f) ? 0x3F80u : 0u;
        float cur1 = fmaf(z1v, w1c[d], b1c[d]);
        float rs1 = (mg1[d * 2 + 1] > 1.f) ? 1.f : 0.f;
        mg1[d * 2 + 1] = 0.85f * mg1[d * 2 + 1] + cur1 - rs1;
        unsigned int bits1 = (mg1[d * 2 + 1] > 1.f) ? 0x3F80u : 0u;
        *(unsigned int*)&spk1T[(2 * cp + d) * 72 + 2 * np] = bits0 | (bits1 << 16);
      }
    }
    __syncthreads();
    {
      const int c = lane & 15;
      const int quad = (lane >> 4) & 3;
      const unsigned short* bp = spk1T + c * 72 + quad * 8;
      v8s B0 = *(const v8s*)(bp);
      v8s B1 = *(const v8s*)(bp + 32);
      v4f acc = {0.f, 0.f, 0.f, 0.f};
      acc = __builtin_amdgcn_mfma_f32_16x16x32_bf16(A_hi[0], B0, acc, 0, 0, 0);
      acc = __builtin_amdgcn_mfma_f32_16x16x32_bf16(A_lo[0], B0, acc, 0, 0, 0);
      acc = __builtin_amdgcn_mfma_f32_16x16x32_bf16(A_hi[1], B1, acc, 0, 0, 0);
      acc = __builtin_amdgcn_mfma_f32_16x16x32_bf16(A_lo[1], B1, acc, 0, 0, 0);
      const int r0 = wv * 16 + quad * 4;
#pragma unroll
      for (int r = 0; r < 4; ++r) Z2f[(r0 + r) * 20 + c] = acc[r];
    }
    __syncthreads();
    if (wv < 2) {
      const int m = lane & 31;
      const int half = lane >> 5;
      const float* zr = Z2f + (wv * 32 + m) * 20 + half * 8;
      float4 za = *(const float4*)zr;
      float4 zb = *(const float4*)(zr + 4);
      float vv[8] = {za.x, za.y, za.z, za.w, zb.x, zb.y, zb.z, zb.w};
      v8s Ah, Al;
#pragma unroll
      for (int e = 0; e < 8; ++e) {
        unsigned short h = bf16t(vv[e]);
        unsigned short l = bf16t(vv[e] - bf16tof(h));
        Ah[e] = (short)h;
        Al[e] = (short)l;
      }
      v16f acc;
#pragma unroll
      for (int r = 0; r < 16; ++r) {
        float rs = (mg2[r] > 1.f) ? 1.f : 0.f;
        acc[r] = fmaf(beta2, mg2[r], b2h - rs);
      }
      acc = __builtin_amdgcn_mfma_f32_32x32x16_bf16(Ah, W_hi, acc, 0, 0, 0);
      acc = __builtin_amdgcn_mfma_f32_32x32x16_bf16(Al, W_hi, acc, 0, 0, 0);
      acc = __builtin_amdgcn_mfma_f32_32x32x16_bf16(Ah, W_lo, acc, 0, 0, 0);
      mg2 = acc;
      unsigned short* pb = pbase + (size_t)t * 2048;
#pragma unroll
      for (int r = 0; r < 16; ++r) {
        int i = wv * 32 + (r & 3) + 8 * (r >> 2) + 4 * half;
        pb[i * 32] = f2h_u(acc[r]);
      }
    }
  }
}

// ================= K3: attention, MFMA f16 (one block per batch) =================
#define PADT 2056  // u16 row stride for potsLds (2048+8)
__global__ __launch_bounds__(256) void k_attn(
    const unsigned short* __restrict__ pots,
    const unsigned short* __restrict__ w1t,
    const float* __restrict__ attn_b1, const float* __restrict__ attn_w2,
    const float* __restrict__ attn_b2,
    unsigned short* __restrict__ ctxh, unsigned short* __restrict__ ctxl)
{
  __shared__ __align__(16) unsigned short potsLds[16 * PADT]; // fp16 [t][i]
  __shared__ float sred[8 * 256];                             // partial [j][tid]
  __shared__ __align__(16) float wbuf[4 * 16];                // per-wave softmax w

  const int tid = threadIdx.x;
  const int lane = tid & 63;
  const int wv = tid >> 6;
  const int m = lane & 15;        // A row (= t)
  const int quad = lane >> 4;     // 0..3
  const int koff = quad * 8;

  // ---- stage pots[b] into LDS (fp16), zero row 15 ----
  {
    const unsigned short* pg = pots + (size_t)blockIdx.x * 30720;
#pragma unroll
    for (int it = 0; it < 15; ++it) {
      int f = (it * 256 + tid) * 8;
      int row = f >> 11, col = f & 2047;
      uint4 v = *(const uint4*)(pg + f);
      *(uint4*)&potsLds[row * PADT + col] = v;
    }
    uint4 z = {0u, 0u, 0u, 0u};
    *(uint4*)&potsLds[15 * PADT + tid * 8] = z;
  }
  __syncthreads();

  // ---- projection: s[t][n] = pots[t]·W1[:,n] via f16 MFMA ----
  v4f a0 = {0.f, 0.f, 0.f, 0.f}, a1 = {0.f, 0.f, 0.f, 0.f};
  {
    const unsigned short* w1ta = w1t + (size_t)m * 2048;        // n = lane&15
    const unsigned short* w1tb = w1t + (size_t)(m + 16) * 2048; // n+16
#pragma unroll 4
    for (int c = 0; c < 16; ++c) {
      const int kb = (wv * 16 + c) * 32 + koff;
      v8h A = *(const v8h*)&potsLds[m * PADT + kb];
      v8h B0 = *(const v8h*)(w1ta + kb);
      v8h B1 = *(const v8h*)(w1tb + kb);
      a0 = __builtin_amdgcn_mfma_f32_16x16x32_f16(A, B0, a0, 0, 0, 0);
      a1 = __builtin_amdgcn_mfma_f32_16x16x32_f16(A, B1, a1, 0, 0, 0);
    }
  }
  // cross-wave reduce of partials
#pragma unroll
  for (int j = 0; j < 4; ++j) {
    sred[j * 256 + tid] = a0[j];
    sred[(j + 4) * 256 + tid] = a1[j];
  }
  __syncthreads();
  float s0[4], s1[4];
#pragma unroll
  for (int j = 0; j < 4; ++j) {
    s0[j] = sred[j * 256 + 0 * 64 + lane] + sred[j * 256 + 1 * 64 + lane]
          + sred[j * 256 + 2 * 64 + lane] + sred[j * 256 + 3 * 64 + lane];
    s1[j] = sred[(j + 4) * 256 + 0 * 64 + lane] + sred[(j + 4) * 256 + 1 * 64 + lane]
          + sred[(j + 4) * 256 + 2 * 64 + lane] + sred[(j + 4) * 256 + 3 * 64 + lane];
  }
  // ---- tanh, n-reduction (within quad), softmax over t ----
  float wlar[16];
  {
    const int n = m;
    const float b1a = attn_b1[n], b1b = attn_b1[n + 16];
    const float w2a = attn_w2[n], w2b = attn_w2[n + 16];
    const float b2 = attn_b2[0];
    float sc[4];
#pragma unroll
    for (int r = 0; r < 4; ++r) {
      float v = tanhf(s0[r] + b1a) * w2a + tanhf(s1[r] + b1b) * w2b;
      v += __shfl_xor(v, 1, 64);
      v += __shfl_xor(v, 2, 64);
      v += __shfl_xor(v, 4, 64);
      v += __shfl_xor(v, 8, 64);
      sc[r] = v + b2;
    }
    float mx = -1e30f;
#pragma unroll
    for (int r = 0; r < 4; ++r) if (quad * 4 + r < 15) mx = fmaxf(mx, sc[r]);
    mx = fmaxf(mx, __shfl_xor(mx, 16, 64));
    mx = fmaxf(mx, __shfl_xor(mx, 32, 64));
    float e[4], den = 0.f;
#pragma unroll
    for (int r = 0; r < 4; ++r) {
      e[r] = (quad * 4 + r < 15) ? expf(sc[r] - mx) : 0.f;
      den += e[r];
    }
    den += __shfl_xor(den, 16, 64);
    den += __shfl_xor(den, 32, 64);
    const float inv = 1.f / den;
    if ((lane & 15) == 0) {
      v4f wq = {e[0] * inv, e[1] * inv, e[2] * inv, e[3] * inv};
      *(v4f*)&wbuf[wv * 16 + quad * 4] = wq;
    }
    // same-wave LDS RAW: ordered by lgkmcnt, no barrier needed
#pragma unroll
    for (int q4 = 0; q4 < 4; ++q4) {
      float4 v = *(const float4*)&wbuf[wv * 16 + q4 * 4];
      wlar[q4 * 4 + 0] = v.x; wlar[q4 * 4 + 1] = v.y;
      wlar[q4 * 4 + 2] = v.z; wlar[q4 * 4 + 3] = v.w;
    }
  }
  // ---- ctx = sum_t w_t * pots[t]  (thread owns 8 contiguous i) ----
  float cv[8] = {0.f, 0.f, 0.f, 0.f, 0.f, 0.f, 0.f, 0.f};
#pragma unroll
  for (int t = 0; t < 15; ++t) {
    v8h pv = *(const v8h*)&potsLds[t * PADT + tid * 8];
    const float w = wlar[t];
#pragma unroll
    for (int j = 0; j < 8; ++j) cv[j] = fmaf(w, (float)pv[j], cv[j]);
  }
  // store ctx as bf16 hi/lo planes
  {
    unsigned short hv[8], lv[8];
#pragma unroll
    for (int j = 0; j < 8; ++j) {
      unsigned short h = bf16t(cv[j]);
      hv[j] = h;
      lv[j] = bf16t(cv[j] - bf16tof(h));
    }
    *(uint4*)(ctxh + (size_t)blockIdx.x * 2048 + tid * 8) = *(const uint4*)hv;
    *(uint4*)(ctxl + (size_t)blockIdx.x * 2048 + tid * 8) = *(const uint4*)lv;
  }
}

// ================= K4: classifier, MFMA bf16 hi/lo (16 rows per block) =================
__global__ __launch_bounds__(256) void k_cls(
    const unsigned short* __restrict__ ctxh, const unsigned short* __restrict__ ctxl,
    const unsigned short* __restrict__ cw1h, const unsigned short* __restrict__ cw1l,
    const float* __restrict__ cls_b1,
    const float* __restrict__ ln_g, const float* __restrict__ ln_b,
    const float* __restrict__ cls_w2, const float* __restrict__ cls_b2,
    float* __restrict__ out, int b0)
{
  __shared__ float hbuf[16 * 132];
  const int tid = threadIdx.x;
  const int lane = tid & 63;
  const int wv = tid >> 6;
  const int m = lane & 15;
  const int quad = lane >> 4;
  const int koff = quad * 8;
  const int r0l = blockIdx.x * 16;

  v4f a0 = {0.f, 0.f, 0.f, 0.f}, a1 = {0.f, 0.f, 0.f, 0.f};
  {
    const unsigned short* Ah = ctxh + (size_t)(r0l + m) * 2048;
    const unsigned short* Al = ctxl + (size_t)(r0l + m) * 2048;
    const int n0 = wv * 32 + m;
    const unsigned short* B0h = cw1h + (size_t)n0 * 2048;
    const unsigned short* B0l = cw1l + (size_t)n0 * 2048;
    const unsigned short* B1h = cw1h + (size_t)(n0 + 16) * 2048;
    const unsigned short* B1l = cw1l + (size_t)(n0 + 16) * 2048;
#pragma unroll 4
    for (int kc = 0; kc < 64; ++kc) {
      const int kb = kc * 32 + koff;
      v8s vAh = *(const v8s*)(Ah + kb);
      v8s vAl = *(const v8s*)(Al + kb);
      v8s vB0h = *(const v8s*)(B0h + kb);
      v8s vB0l = *(const v8s*)(B0l + kb);
      v8s vB1h = *(const v8s*)(B1h + kb);
      v8s vB1l = *(const v8s*)(B1l + kb);
      a0 = __builtin_amdgcn_mfma_f32_16x16x32_bf16(vAh, vB0h, a0, 0, 0, 0);
      a0 = __builtin_amdgcn_mfma_f32_16x16x32_bf16(vAl, vB0h, a0, 0, 0, 0);
      a0 = __builtin_amdgcn_mfma_f32_16x16x32_bf16(vAh, vB0l, a0, 0, 0, 0);
      a1 = __builtin_amdgcn_mfma_f32_16x16x32_bf16(vAh, vB1h, a1, 0, 0, 0);
      a1 = __builtin_amdgcn_mfma_f32_16x16x32_bf16(vAl, vB1h, a1, 0, 0, 0);
      a1 = __builtin_amdgcn_mfma_f32_16x16x32_bf16(vAh, vB1l, a1, 0, 0, 0);
    }
  }
  {
    const int n0 = wv * 32 + m;
    const float bb0 = cls_b1[n0], bb1 = cls_b1[n0 + 16];
#pragma unroll
    for (int r = 0; r < 4; ++r) {
      const int row = quad * 4 + r;
      hbuf[row * 132 + n0] = a0[r] + bb0;
      hbuf[row * 132 + n0 + 16] = a1[r] + bb1;
    }
  }
  __syncthreads();
  // LayerNorm + GELU(exact) + final 128x4
  const float g0c = ln_g[lane], g1c = ln_g[lane + 64];
  const float b0c = ln_b[lane], b1c = ln_b[lane + 64];
  const float4 w2a = *(const float4*)(cls_w2 + lane * 4);
  const float4 w2b = *(const float4*)(cls_w2 + (lane + 64) * 4);
#pragma unroll
  for (int rr = 0; rr < 4; ++rr) {
    const int r = wv * 4 + rr;
    const float x0 = hbuf[r * 132 + lane];
    const float x1 = hbuf[r * 132 + 64 + lane];
    float s = x0 + x1, sq = x0 * x0 + x1 * x1;
#pragma unroll
    for (int mm = 32; mm >= 1; mm >>= 1) {
      s += __shfl_xor(s, mm, 64);
      sq += __shfl_xor(sq, mm, 64);
    }
    const float mu = s * (1.f / 128.f);
    const float var = sq * (1.f / 128.f) - mu * mu;
    const float rstd = rsqrtf(var + 1e-5f);
    float h0 = (x0 - mu) * rstd * g0c + b0c;
    float h1 = (x1 - mu) * rstd * g1c + b1c;
    h0 = 0.5f * h0 * (1.f + erff(h0 * 0.7071067811865475f));
    h1 = 0.5f * h1 * (1.f + erff(h1 * 0.7071067811865475f));
    float o0 = h0 * w2a.x + h1 * w2b.x;
    float o1 = h0 * w2a.y + h1 * w2b.y;
    float o2 = h0 * w2a.z + h1 * w2b.z;
    float o3 = h0 * w2a.w + h1 * w2b.w;
#pragma unroll
    for (int mm = 32; mm >= 1; mm >>= 1) {
      o0 += __shfl_xor(o0, mm, 64);
      o1 += __shfl_xor(o1, mm, 64);
      o2 += __shfl_xor(o2, mm, 64);
      o3 += __shfl_xor(o3, mm, 64);
    }
    if (lane == 0) {
      *(float4*)(out + (size_t)(b0 + r0l + r) * 4) =
          make_float4(o0 + cls_b2[0], o1 + cls_b2[1], o2 + cls_b2[2], o3 + cls_b2[3]);
    }
  }
}

// ================= host =================
extern "C" void kernel_launch(void* const* d_in, const int* in_sizes, int n_in,
                              void* d_out, int out_size, void* d_ws, size_t ws_size,
                              hipStream_t stream) {
  const float* L_norm   = (const float*)d_in[0];
  const float* X_seq    = (const float*)d_in[1];
  const float* conv_w   = (const float*)d_in[2];
  const float* conv_b   = (const float*)d_in[3];
  const float* bn_gamma = (const float*)d_in[4];
  const float* bn_beta  = (const float*)d_in[5];
  const float* bn_mean  = (const float*)d_in[6];
  const float* bn_var   = (const float*)d_in[7];
  const float* gcn1_w   = (const float*)d_in[8];
  const float* gcn1_b   = (const float*)d_in[9];
  const float* gcn2_w   = (const float*)d_in[11];
  const float* gcn2_b   = (const float*)d_in[12];
  const float* mask1    = (const float*)d_in[10];
  const float* mask2    = (const float*)d_in[13];
  const float* beta2    = (const float*)d_in[14];
  const float* attn_w1  = (const float*)d_in[15];
  const float* attn_b1  = (const float*)d_in[16];
  const float* attn_w2  = (const float*)d_in[17];
  const float* attn_b2  = (const float*)d_in[18];
  const float* cls_w1   = (const float*)d_in[19];
  const float* cls_b1   = (const float*)d_in[20];
  const float* ln_gamma = (const float*)d_in[21];
  const float* ln_beta  = (const float*)d_in[22];
  const float* cls_w2   = (const float*)d_in[23];
  const float* cls_b2   = (const float*)d_in[24];

  char* ws = (char*)d_ws;
  float* wsf = (float*)d_ws;
  unsigned short* w1t  = (unsigned short*)(ws + OFF_W1T);
  unsigned short* cw1h = (unsigned short*)(ws + OFF_CW1H);
  unsigned short* cw1l = (unsigned short*)(ws + OFF_CW1L);

  long long avail = (long long)ws_size - (long long)OFF_DYN;
  long long per = PER_BATCH_POTS_B + PER_BATCH_CTX_B;
  int chunk = 4096;
  if (avail < per * 4096LL) {
    long long c = (avail > 0) ? (avail / per) : 16;
    if (c > 4096) c = 4096;
    c &= ~15LL;
    if (c < 16) c = 16;
    chunk = (int)c;
  }
  unsigned short* pots = (unsigned short*)(ws + OFF_DYN);
  unsigned short* ctxh = (unsigned short*)(ws + OFF_DYN + (size_t)chunk * PER_BATCH_POTS_B);
  unsigned short* ctxl = ctxh + (size_t)chunk * 2048;

  hipLaunchKernelGGL(k_prep, dim3(64), dim3(256), 0, stream,
                     mask1, mask2, conv_w, conv_b, bn_gamma, bn_beta, bn_mean, bn_var,
                     attn_w1, cls_w1, wsf, w1t, cw1h, cw1l);

  for (int b0 = 0; b0 < 4096; b0 += chunk) {
    int cur = 4096 - b0;
    if (cur > chunk) cur = chunk;
    hipLaunchKernelGGL(k_main, dim3(cur), dim3(256), 0, stream,
                       L_norm, X_seq, gcn1_w, gcn1_b, gcn2_w, gcn2_b, beta2,
                       wsf, pots, b0);
    hipLaunchKernelGGL(k_attn, dim3(cur), dim3(256), 0, stream,
                       pots, w1t, attn_b1, attn_w2, attn_b2, ctxh, ctxl);
    hipLaunchKernelGGL(k_cls, dim3(cur / 16), dim3(256), 0, stream,
                       ctxh, ctxl, cw1h, cw1l, cls_b1, ln_gamma, ln_beta, cls_w2, cls_b2,
                       (float*)d_out, b0);
  }
}